// Round 6
// baseline (193.036 us; speedup 1.0000x reference)
//
#include <hip/hip_runtime.h>
#include <hip/hip_bf16.h>
#include <math.h>

constexpr int B = 8, N = 2048, H = 512, A = 128;

typedef __bf16 bf16x8 __attribute__((ext_vector_type(8)));
typedef float f32x4 __attribute__((ext_vector_type(4)));
typedef unsigned short ushort_t;
typedef unsigned int uint_t;

__device__ __forceinline__ f32x4 mfma16(bf16x8 a, bf16x8 b, f32x4 c) {
    return __builtin_amdgcn_mfma_f32_16x16x32_bf16(a, b, c, 0, 0, 0);
}
__device__ __forceinline__ ushort_t f2bf(float v) {
    return __builtin_bit_cast(ushort_t, __float2bfloat16(v));
}
__device__ __forceinline__ float bf2f(ushort_t u) {
    return __bfloat162float(__builtin_bit_cast(__hip_bfloat16, u));
}

// ---------------- K0: transpose + hi/lo split the weights ----------------
__global__ __launch_bounds__(256) void k0_conv(
    const float* __restrict__ Wq, const float* __restrict__ Wk,
    ushort_t* __restrict__ WqTh, ushort_t* __restrict__ WqTl,
    ushort_t* __restrict__ WkTh, ushort_t* __restrict__ WkTl)
{
    const int id = blockIdx.x * 256 + threadIdx.x;   // 65536 = 512*128
    const int k = id >> 7, n = id & 127;
    const float vq = Wq[id];
    const ushort_t qh = f2bf(vq);
    const ushort_t ql = f2bf(vq - bf2f(qh));
    WqTh[n * 512 + k] = qh; WqTl[n * 512 + k] = ql;
    const float vk = Wk[id];
    const ushort_t kh = f2bf(vk);
    const ushort_t kl = f2bf(vk - bf2f(kh));
    WkTh[n * 512 + k] = kh; WkTl[n * 512 + k] = kl;
}

// ---------------- K1: MFMA projections + gate; stores hi/lo planes ----------------
__global__ __launch_bounds__(256) void k1_mfma(
    const float* __restrict__ x,
    const ushort_t* __restrict__ WqTh, const ushort_t* __restrict__ WqTl,
    const ushort_t* __restrict__ WkTh, const ushort_t* __restrict__ WkTl,
    const float* __restrict__ bq, const float* __restrict__ bk,
    const float* __restrict__ Wv, const float* __restrict__ bv,
    ushort_t* __restrict__ Qhi, ushort_t* __restrict__ Qlo,
    ushort_t* __restrict__ Khi, ushort_t* __restrict__ Klo, float* __restrict__ gb)
{
    __shared__ ushort_t xh[64 * 256], xl[64 * 256];   // 64 KiB
    __shared__ float gred[2][64];
    const int t = threadIdx.x;
    const int lane = t & 63, w = t >> 6;
    const int l15 = lane & 15, l4 = lane >> 4;
    const int m0 = blockIdx.x * 64;

    f32x4 acc[4][4];
    #pragma unroll
    for (int r = 0; r < 4; ++r)
        #pragma unroll
        for (int c = 0; c < 4; ++c) acc[r][c] = {0.f, 0.f, 0.f, 0.f};

    const ushort_t* WTh = (w < 2) ? WqTh : WkTh;
    const ushort_t* WTl = (w < 2) ? WqTl : WkTl;
    const int colbase = (w & 1) * 64;

    for (int ck = 0; ck < 2; ++ck) {
        __syncthreads();
        #pragma unroll
        for (int it = 0; it < 16; ++it) {
            const int idx = it * 256 + t;
            const int row = idx >> 6, c4 = idx & 63;
            const float4 v = *(const float4*)(x + (size_t)(m0 + row) * H + ck * 256 + c4 * 4);
            const ushort_t h0 = f2bf(v.x), h1 = f2bf(v.y), h2 = f2bf(v.z), h3 = f2bf(v.w);
            const ushort_t e0 = f2bf(v.x - bf2f(h0)), e1 = f2bf(v.y - bf2f(h1));
            const ushort_t e2 = f2bf(v.z - bf2f(h2)), e3 = f2bf(v.w - bf2f(h3));
            uint2 hh, ll;
            hh.x = (uint_t)h0 | ((uint_t)h1 << 16); hh.y = (uint_t)h2 | ((uint_t)h3 << 16);
            ll.x = (uint_t)e0 | ((uint_t)e1 << 16); ll.y = (uint_t)e2 | ((uint_t)e3 << 16);
            const int base = row * 512 + ((((c4 >> 1) << 4)) ^ ((row & 7) << 4)) + (c4 & 1) * 8;
            *(uint2*)((char*)xh + base) = hh;
            *(uint2*)((char*)xl + base) = ll;
        }
        __syncthreads();

        #pragma unroll
        for (int ks = 0; ks < 8; ++ks) {
            bf16x8 ah[4], al[4], bh[4], bl[4];
            const int kb = ks * 64 + l4 * 16;
            #pragma unroll
            for (int rb = 0; rb < 4; ++rb) {
                const int row = rb * 16 + l15;
                const int off = row * 512 + (kb ^ ((row & 7) << 4));
                ah[rb] = *(const bf16x8*)((const char*)xh + off);
                al[rb] = *(const bf16x8*)((const char*)xl + off);
            }
            const int kg = ck * 256 + ks * 32 + l4 * 8;
            #pragma unroll
            for (int cb = 0; cb < 4; ++cb) {
                const size_t woff = (size_t)(colbase + cb * 16 + l15) * 512 + kg;
                bh[cb] = *(const bf16x8*)(WTh + woff);
                bl[cb] = *(const bf16x8*)(WTl + woff);
            }
            #pragma unroll
            for (int rb = 0; rb < 4; ++rb)
                #pragma unroll
                for (int cb = 0; cb < 4; ++cb) {
                    acc[rb][cb] = mfma16(ah[rb], bh[cb], acc[rb][cb]);
                    acc[rb][cb] = mfma16(ah[rb], bl[cb], acc[rb][cb]);
                    acc[rb][cb] = mfma16(al[rb], bh[cb], acc[rb][cb]);
                }
        }
    }

    const float* bias = (w < 2) ? bq : bk;
    float bb[4], wv[4];
    #pragma unroll
    for (int cb = 0; cb < 4; ++cb) {
        bb[cb] = bias[colbase + cb * 16 + l15];
        wv[cb] = Wv[colbase + cb * 16 + l15];
    }
    float p[4][4];
    #pragma unroll
    for (int rb = 0; rb < 4; ++rb)
        #pragma unroll
        for (int g = 0; g < 4; ++g) {
            float ps = 0.f;
            #pragma unroll
            for (int cb = 0; cb < 4; ++cb) {
                const float v = acc[rb][cb][g] + bb[cb];
                acc[rb][cb][g] = v;
                ps = fmaf(v, wv[cb], ps);
            }
            p[rb][g] = ps;
        }

    ushort_t* OH = (w < 2) ? Qhi : Khi;
    ushort_t* OL = (w < 2) ? Qlo : Klo;
    #pragma unroll
    for (int rb = 0; rb < 4; ++rb) {
        const int row = m0 + rb * 16 + l4 * 4;
        #pragma unroll
        for (int cb = 0; cb < 4; ++cb) {
            const int col = colbase + cb * 16 + l15;
            #pragma unroll
            for (int g = 0; g < 4; ++g) {
                const float v = acc[rb][cb][g];
                const ushort_t hi = f2bf(v);
                const ushort_t lo = f2bf(v - bf2f(hi));
                OH[(size_t)(row + g) * A + col] = hi;
                OL[(size_t)(row + g) * A + col] = lo;
            }
        }
    }

    if (w < 2) {
        #pragma unroll
        for (int rb = 0; rb < 4; ++rb)
            #pragma unroll
            for (int g = 0; g < 4; ++g) {
                float v = p[rb][g];
                v += __shfl_xor(v, 1); v += __shfl_xor(v, 2);
                v += __shfl_xor(v, 4); v += __shfl_xor(v, 8);
                if (l15 == 0) gred[w][rb * 16 + l4 * 4 + g] = v;
            }
    }
    __syncthreads();
    if (t < 64) {
        const float z = gred[0][t] + gred[1][t] + bv[0];
        gb[m0 + t] = 1.f / (1.f + __expf(-z));
    }
}

// ---------------- K2: fused scores->exp->rowsum->normalize->out ----------------
// 1024 WGs x 512 threads (8 waves). WG owns (b = bid&7, 16-row i-block).
// Operand-swapped MFMA: acc lane holds (i = lane&15, 4 consecutive j).
// e-tile in LDS: 16 rows x 2052-ushort stride (66 KB) -> 2 WGs/CU.
__global__ __launch_bounds__(512, 4) void k2_fused(
    const ushort_t* __restrict__ Qhi, const ushort_t* __restrict__ Qlo,
    const ushort_t* __restrict__ Khi, const ushort_t* __restrict__ Klo,
    const float* __restrict__ gb, float* __restrict__ out)
{
    constexpr int ESTRIDE = 2052;            // ushorts per row (padded)
    __shared__ ushort_t elds[16 * ESTRIDE];  // ~66 KB
    __shared__ float lred[8][16];
    __shared__ float scv[16], gvv[16];
    const int t = threadIdx.x;
    const int lane = t & 63, w = t >> 6;
    const int l15 = lane & 15, l4 = lane >> 4;
    const int b  = blockIdx.x & 7;           // XCD-aligned batch
    const int i0 = (blockIdx.x >> 3) * 16;
    const size_t bN = (size_t)b * N;
    const int i = i0 + l15;                  // this lane's output row

    // Q fragments (B-operand): 8 x bf16x8 = 32 VGPRs, live whole kernel
    bf16x8 qh_[4], ql_[4];
    {
        const size_t ro = (bN + i) * A + l4 * 8;
        #pragma unroll
        for (int ks = 0; ks < 4; ++ks) {
            qh_[ks] = *(const bf16x8*)(Qhi + ro + ks * 32);
            ql_[ks] = *(const bf16x8*)(Qlo + ro + ks * 32);
        }
    }

    float lsum = 0.f;

    for (int jt = 0; jt < 8; ++jt) {
        const int jb = jt * 256 + w * 32;

        f32x4 acc[2];
        acc[0] = {0.f, 0.f, 0.f, 0.f};
        acc[1] = {0.f, 0.f, 0.f, 0.f};

        #pragma unroll
        for (int ks = 0; ks < 4; ++ks) {
            bf16x8 kh_[2], kl_[2];
            #pragma unroll
            for (int cf = 0; cf < 2; ++cf) {
                const size_t co = (bN + jb + cf * 16 + l15) * A + ks * 32 + l4 * 8;
                kh_[cf] = *(const bf16x8*)(Khi + co);
                kl_[cf] = *(const bf16x8*)(Klo + co);
            }
            #pragma unroll
            for (int cf = 0; cf < 2; ++cf) {
                acc[cf] = mfma16(kh_[cf], qh_[ks], acc[cf]);
                acc[cf] = mfma16(kl_[cf], qh_[ks], acc[cf]);
                acc[cf] = mfma16(kh_[cf], ql_[ks], acc[cf]);
            }
        }

        // epilogue: lane holds rows i, cols j0..j0+3 per cf
        #pragma unroll
        for (int cf = 0; cf < 2; ++cf) {
            const int j0 = jb + cf * 16 + l4 * 4;
            float e0 = (i == j0 + 0) ? 0.f : __expf(acc[cf][0]);
            float e1 = (i == j0 + 1) ? 0.f : __expf(acc[cf][1]);
            float e2 = (i == j0 + 2) ? 0.f : __expf(acc[cf][2]);
            float e3 = (i == j0 + 3) ? 0.f : __expf(acc[cf][3]);
            lsum += (e0 + e1) + (e2 + e3);
            uint2 pk;
            pk.x = (uint_t)f2bf(e0) | ((uint_t)f2bf(e1) << 16);
            pk.y = (uint_t)f2bf(e2) | ((uint_t)f2bf(e3) << 16);
            *(uint2*)((char*)elds + l15 * (ESTRIDE * 2) + j0 * 2) = pk;
        }
    }

    // row-sum: combine l4 groups in-wave, then across the 8 waves
    lsum += __shfl_xor(lsum, 16);
    lsum += __shfl_xor(lsum, 32);
    if (lane < 16) lred[w][l15] = lsum;
    __syncthreads();
    if (t < 16) {
        float l = 0.f;
        #pragma unroll
        for (int ww = 0; ww < 8; ++ww) l += lred[ww][t];
        const float gv = gb[bN + i0 + t];
        gvv[t] = gv;
        scv[t] = (1.f - gv) / l;
    }
    __syncthreads();

    // normalize + diagonal + coalesced f32 store
    #pragma unroll
    for (int it = 0; it < 8; ++it) {
        const int chunk = it * 512 + t;          // 0..4095
        const int ri = chunk >> 8;               // 16 rows
        const int c0 = (chunk & 255) * 8;
        const float sc = scv[ri], gv = gvv[ri];
        const int irow = i0 + ri;
        const char* src = (const char*)elds + ri * (ESTRIDE * 2) + c0 * 2;
        const uint2 ea = *(const uint2*)src;
        const uint2 eb = *(const uint2*)(src + 8);
        float4 o0, o1;
        o0.x = (c0 + 0 == irow) ? gv : bf2f((ushort_t)(ea.x & 0xffffu)) * sc;
        o0.y = (c0 + 1 == irow) ? gv : bf2f((ushort_t)(ea.x >> 16)) * sc;
        o0.z = (c0 + 2 == irow) ? gv : bf2f((ushort_t)(ea.y & 0xffffu)) * sc;
        o0.w = (c0 + 3 == irow) ? gv : bf2f((ushort_t)(ea.y >> 16)) * sc;
        o1.x = (c0 + 4 == irow) ? gv : bf2f((ushort_t)(eb.x & 0xffffu)) * sc;
        o1.y = (c0 + 5 == irow) ? gv : bf2f((ushort_t)(eb.x >> 16)) * sc;
        o1.z = (c0 + 6 == irow) ? gv : bf2f((ushort_t)(eb.y & 0xffffu)) * sc;
        o1.w = (c0 + 7 == irow) ? gv : bf2f((ushort_t)(eb.y >> 16)) * sc;
        float* dst = out + (bN + irow) * N + c0;
        *(float4*)dst = o0;
        *(float4*)(dst + 4) = o1;
    }
}

extern "C" void kernel_launch(void* const* d_in, const int* in_sizes, int n_in,
                              void* d_out, int out_size, void* d_ws, size_t ws_size,
                              hipStream_t stream) {
    const float* x  = (const float*)d_in[0];
    const float* Wq = (const float*)d_in[1];
    const float* bq = (const float*)d_in[2];
    const float* Wk = (const float*)d_in[3];
    const float* bk = (const float*)d_in[4];
    const float* Wv = (const float*)d_in[5];
    const float* bv = (const float*)d_in[6];
    float* out = (float*)d_out;

    const size_t BNA = (size_t)B * N * A;
    ushort_t* Qhi = (ushort_t*)d_ws;                     // 4 MB each
    ushort_t* Qlo = Qhi + BNA;
    ushort_t* Khi = Qlo + BNA;
    ushort_t* Klo = Khi + BNA;
    ushort_t* WqTh = Klo + BNA;
    ushort_t* WqTl = WqTh + H * A;
    ushort_t* WkTh = WqTl + H * A;
    ushort_t* WkTl = WkTh + H * A;
    float* gb = (float*)(WkTl + H * A);                  // 64 KB

    k0_conv<<<(H * A) / 256, 256, 0, stream>>>(Wq, Wk, WqTh, WqTl, WkTh, WkTl);
    k1_mfma<<<(B * N) / 64, 256, 0, stream>>>(x, WqTh, WqTl, WkTh, WkTl,
                                              bq, bk, Wv, bv, Qhi, Qlo, Khi, Klo, gb);
    k2_fused<<<B * (N / 16), 512, 0, stream>>>(Qhi, Qlo, Khi, Klo, gb, out);
}

// Round 7
// 129.945 us; speedup vs baseline: 1.4855x; 1.4855x over previous
//
#include <hip/hip_runtime.h>
#include <hip/hip_bf16.h>
#include <math.h>

constexpr int B = 8, N = 2048, H = 512, A = 128;

typedef __bf16 bf16x8 __attribute__((ext_vector_type(8)));
typedef float f32x4 __attribute__((ext_vector_type(4)));
typedef unsigned short ushort_t;
typedef unsigned int uint_t;

__device__ __forceinline__ f32x4 mfma16(bf16x8 a, bf16x8 b, f32x4 c) {
    return __builtin_amdgcn_mfma_f32_16x16x32_bf16(a, b, c, 0, 0, 0);
}
__device__ __forceinline__ ushort_t f2bf(float v) {
    return __builtin_bit_cast(ushort_t, __float2bfloat16(v));
}
__device__ __forceinline__ float bf2f(ushort_t u) {
    return __bfloat162float(__builtin_bit_cast(__hip_bfloat16, u));
}

// ---------------- K0: transpose + hi/lo split the weights ----------------
__global__ __launch_bounds__(256) void k0_conv(
    const float* __restrict__ Wq, const float* __restrict__ Wk,
    ushort_t* __restrict__ WqTh, ushort_t* __restrict__ WqTl,
    ushort_t* __restrict__ WkTh, ushort_t* __restrict__ WkTl)
{
    const int id = blockIdx.x * 256 + threadIdx.x;   // 65536 = 512*128
    const int k = id >> 7, n = id & 127;
    const float vq = Wq[id];
    const ushort_t qh = f2bf(vq);
    const ushort_t ql = f2bf(vq - bf2f(qh));
    WqTh[n * 512 + k] = qh; WqTl[n * 512 + k] = ql;
    const float vk = Wk[id];
    const ushort_t kh = f2bf(vk);
    const ushort_t kl = f2bf(vk - bf2f(kh));
    WkTh[n * 512 + k] = kh; WkTl[n * 512 + k] = kl;
}

// ---------------- K1: MFMA projections + gate (packed hi/lo stores) ----------------
__global__ __launch_bounds__(256) void k1_mfma(
    const float* __restrict__ x,
    const ushort_t* __restrict__ WqTh, const ushort_t* __restrict__ WqTl,
    const ushort_t* __restrict__ WkTh, const ushort_t* __restrict__ WkTl,
    const float* __restrict__ bq, const float* __restrict__ bk,
    const float* __restrict__ Wv, const float* __restrict__ bv,
    uint_t* __restrict__ QP, uint_t* __restrict__ KP, float* __restrict__ gb)
{
    __shared__ ushort_t xh[64 * 256], xl[64 * 256];   // 64 KiB
    __shared__ float gred[2][64];
    const int t = threadIdx.x;
    const int lane = t & 63, w = t >> 6;
    const int l15 = lane & 15, l4 = lane >> 4;
    const int m0 = blockIdx.x * 64;

    f32x4 acc[4][4];
    #pragma unroll
    for (int r = 0; r < 4; ++r)
        #pragma unroll
        for (int c = 0; c < 4; ++c) acc[r][c] = {0.f, 0.f, 0.f, 0.f};

    const ushort_t* WTh = (w < 2) ? WqTh : WkTh;
    const ushort_t* WTl = (w < 2) ? WqTl : WkTl;
    const int colbase = (w & 1) * 64;

    for (int ck = 0; ck < 2; ++ck) {
        __syncthreads();
        #pragma unroll
        for (int it = 0; it < 16; ++it) {
            const int idx = it * 256 + t;
            const int row = idx >> 6, c4 = idx & 63;
            const float4 v = *(const float4*)(x + (size_t)(m0 + row) * H + ck * 256 + c4 * 4);
            const ushort_t h0 = f2bf(v.x), h1 = f2bf(v.y), h2 = f2bf(v.z), h3 = f2bf(v.w);
            const ushort_t e0 = f2bf(v.x - bf2f(h0)), e1 = f2bf(v.y - bf2f(h1));
            const ushort_t e2 = f2bf(v.z - bf2f(h2)), e3 = f2bf(v.w - bf2f(h3));
            uint2 hh, ll;
            hh.x = (uint_t)h0 | ((uint_t)h1 << 16); hh.y = (uint_t)h2 | ((uint_t)h3 << 16);
            ll.x = (uint_t)e0 | ((uint_t)e1 << 16); ll.y = (uint_t)e2 | ((uint_t)e3 << 16);
            const int base = row * 512 + ((((c4 >> 1) << 4)) ^ ((row & 7) << 4)) + (c4 & 1) * 8;
            *(uint2*)((char*)xh + base) = hh;
            *(uint2*)((char*)xl + base) = ll;
        }
        __syncthreads();

        #pragma unroll
        for (int ks = 0; ks < 8; ++ks) {
            bf16x8 ah[4], al[4], bh[4], bl[4];
            const int kb = ks * 64 + l4 * 16;
            #pragma unroll
            for (int rb = 0; rb < 4; ++rb) {
                const int row = rb * 16 + l15;
                const int off = row * 512 + (kb ^ ((row & 7) << 4));
                ah[rb] = *(const bf16x8*)((const char*)xh + off);
                al[rb] = *(const bf16x8*)((const char*)xl + off);
            }
            const int kg = ck * 256 + ks * 32 + l4 * 8;
            #pragma unroll
            for (int cb = 0; cb < 4; ++cb) {
                const size_t woff = (size_t)(colbase + cb * 16 + l15) * 512 + kg;
                bh[cb] = *(const bf16x8*)(WTh + woff);
                bl[cb] = *(const bf16x8*)(WTl + woff);
            }
            #pragma unroll
            for (int rb = 0; rb < 4; ++rb)
                #pragma unroll
                for (int cb = 0; cb < 4; ++cb) {
                    acc[rb][cb] = mfma16(ah[rb], bh[cb], acc[rb][cb]);
                    acc[rb][cb] = mfma16(ah[rb], bl[cb], acc[rb][cb]);
                    acc[rb][cb] = mfma16(al[rb], bh[cb], acc[rb][cb]);
                }
        }
    }

    const float* bias = (w < 2) ? bq : bk;
    float bb[4], wv[4];
    #pragma unroll
    for (int cb = 0; cb < 4; ++cb) {
        bb[cb] = bias[colbase + cb * 16 + l15];
        wv[cb] = Wv[colbase + cb * 16 + l15];
    }
    float p[4][4];
    #pragma unroll
    for (int rb = 0; rb < 4; ++rb)
        #pragma unroll
        for (int g = 0; g < 4; ++g) {
            float ps = 0.f;
            #pragma unroll
            for (int cb = 0; cb < 4; ++cb) {
                const float v = acc[rb][cb][g] + bb[cb];
                acc[rb][cb][g] = v;
                ps = fmaf(v, wv[cb], ps);
            }
            p[rb][g] = ps;
        }

    uint_t* OP = (w < 2) ? QP : KP;
    #pragma unroll
    for (int rb = 0; rb < 4; ++rb) {
        const int row = m0 + rb * 16 + l4 * 4;
        #pragma unroll
        for (int cb = 0; cb < 4; ++cb) {
            const int col = colbase + cb * 16 + l15;
            #pragma unroll
            for (int g = 0; g < 4; ++g) {
                const float v = acc[rb][cb][g];
                const ushort_t hi = f2bf(v);
                const ushort_t lo = f2bf(v - bf2f(hi));
                OP[(size_t)(row + g) * A + col] = (uint_t)hi | ((uint_t)lo << 16);
            }
        }
    }

    if (w < 2) {
        #pragma unroll
        for (int rb = 0; rb < 4; ++rb)
            #pragma unroll
            for (int g = 0; g < 4; ++g) {
                float v = p[rb][g];
                v += __shfl_xor(v, 1); v += __shfl_xor(v, 2);
                v += __shfl_xor(v, 4); v += __shfl_xor(v, 8);
                if (l15 == 0) gred[w][rb * 16 + l4 * 4 + g] = v;
            }
    }
    __syncthreads();
    if (t < 64) {
        const float z = gred[0][t] + gred[1][t] + bv[0];
        gb[m0 + t] = 1.f / (1.f + __expf(-z));
    }
}

// ---------------- K2s: pass 1 — scores -> exp -> partial row sums (no store) ----------------
__global__ __launch_bounds__(256) void k2s_mfma(
    const uint_t* __restrict__ QP, const uint_t* __restrict__ KP,
    float* __restrict__ lpart)
{
    __shared__ ushort_t qh[128*128], ql[128*128], kh[128*128], kl[128*128]; // 128 KiB
    const int t = threadIdx.x;
    const int lane = t & 63, wid = t >> 6;
    const int wr = wid >> 1, wc = wid & 1;
    const int l15 = lane & 15, l4 = lane >> 4;

    const int jc = blockIdx.x & 3;
    const int rb_ = blockIdx.x >> 2;
    const int b  = rb_ >> 4;
    const int i0 = (rb_ & 15) * 128;

    {
        const uint4* sq = (const uint4*)(QP + ((size_t)b * N + i0) * A);
        #pragma unroll
        for (int it = 0; it < 16; ++it) {
            const int idx = it * 256 + t;
            const int row = idx >> 5, c4 = idx & 31;
            const uint4 v = sq[idx];
            uint2 hh, ll;
            hh.x = (v.x & 0xffffu) | ((v.y & 0xffffu) << 16);
            hh.y = (v.z & 0xffffu) | ((v.w & 0xffffu) << 16);
            ll.x = (v.x >> 16) | (v.y & 0xffff0000u);
            ll.y = (v.z >> 16) | (v.w & 0xffff0000u);
            const int base = (row << 8) + (((c4 >> 1) << 4) ^ ((row & 7) << 4)) + (c4 & 1) * 8;
            *(uint2*)((char*)qh + base) = hh;
            *(uint2*)((char*)ql + base) = ll;
        }
    }

    float lsum[16];
    #pragma unroll
    for (int u = 0; u < 16; ++u) lsum[u] = 0.f;

    for (int jt = 0; jt < 4; ++jt) {
        const int j0 = jc * 512 + jt * 128;
        __syncthreads();
        {
            const uint4* sk = (const uint4*)(KP + ((size_t)b * N + j0) * A);
            #pragma unroll
            for (int it = 0; it < 16; ++it) {
                const int idx = it * 256 + t;
                const int row = idx >> 5, c4 = idx & 31;
                const uint4 v = sk[idx];
                uint2 hh, ll;
                hh.x = (v.x & 0xffffu) | ((v.y & 0xffffu) << 16);
                hh.y = (v.z & 0xffffu) | ((v.w & 0xffffu) << 16);
                ll.x = (v.x >> 16) | (v.y & 0xffff0000u);
                ll.y = (v.z >> 16) | (v.w & 0xffff0000u);
                const int base = (row << 8) + (((c4 >> 1) << 4) ^ ((row & 7) << 4)) + (c4 & 1) * 8;
                *(uint2*)((char*)kh + base) = hh;
                *(uint2*)((char*)kl + base) = ll;
            }
        }
        __syncthreads();

        f32x4 acc[4][4];
        #pragma unroll
        for (int r = 0; r < 4; ++r)
            #pragma unroll
            for (int c = 0; c < 4; ++c) acc[r][c] = {0.f, 0.f, 0.f, 0.f};

        #pragma unroll
        for (int ks = 0; ks < 4; ++ks) {
            const int kb = ks * 64 + l4 * 16;
            bf16x8 ah[4], al[4], bh[4], bl[4];
            #pragma unroll
            for (int r = 0; r < 4; ++r) {
                const int row = wr * 64 + r * 16 + l15;
                const int off = (row << 8) + (kb ^ ((row & 7) << 4));
                ah[r] = *(const bf16x8*)((const char*)qh + off);
                al[r] = *(const bf16x8*)((const char*)ql + off);
            }
            #pragma unroll
            for (int c = 0; c < 4; ++c) {
                const int row = wc * 64 + c * 16 + l15;
                const int off = (row << 8) + (kb ^ ((row & 7) << 4));
                bh[c] = *(const bf16x8*)((const char*)kh + off);
                bl[c] = *(const bf16x8*)((const char*)kl + off);
            }
            #pragma unroll
            for (int r = 0; r < 4; ++r)
                #pragma unroll
                for (int c = 0; c < 4; ++c) {
                    acc[r][c] = mfma16(ah[r], bh[c], acc[r][c]);
                    acc[r][c] = mfma16(ah[r], bl[c], acc[r][c]);
                    acc[r][c] = mfma16(al[r], bh[c], acc[r][c]);
                }
        }

        #pragma unroll
        for (int r = 0; r < 4; ++r) {
            const int i = i0 + wr * 64 + r * 16 + l4 * 4;
            #pragma unroll
            for (int c = 0; c < 4; ++c) {
                const int j = j0 + wc * 64 + c * 16 + l15;
                #pragma unroll
                for (int g = 0; g < 4; ++g) {
                    const float e = (i + g == j) ? 0.f : __expf(acc[r][c][g]);
                    lsum[r * 4 + g] += e;
                }
            }
        }
    }

    __syncthreads();
    float* lred = (float*)kh;
    #pragma unroll
    for (int r = 0; r < 4; ++r)
        #pragma unroll
        for (int g = 0; g < 4; ++g) {
            float v = lsum[r * 4 + g];
            v += __shfl_xor(v, 1); v += __shfl_xor(v, 2);
            v += __shfl_xor(v, 4); v += __shfl_xor(v, 8);
            if (l15 == 0) lred[wc * 128 + wr * 64 + r * 16 + l4 * 4 + g] = v;
        }
    __syncthreads();
    if (t < 128)
        lpart[(size_t)jc * (B * N) + (size_t)b * N + i0 + t] = lred[t] + lred[128 + t];
}

// ---------------- K2w: pass 2 — recompute scores -> normalize -> f32 out ----------------
__global__ __launch_bounds__(256) void k2w_mfma(
    const uint_t* __restrict__ QP, const uint_t* __restrict__ KP,
    const float* __restrict__ gb, const float* __restrict__ lpart,
    float* __restrict__ out)
{
    __shared__ ushort_t qh[128*128], ql[128*128], kh[128*128], kl[128*128]; // 128 KiB
    __shared__ float scl_s[128], gvv_s[128];
    const int t = threadIdx.x;
    const int lane = t & 63, wid = t >> 6;
    const int wr = wid >> 1, wc = wid & 1;
    const int l15 = lane & 15, l4 = lane >> 4;

    const int jc = blockIdx.x & 3;
    const int rb_ = blockIdx.x >> 2;
    const int b  = rb_ >> 4;
    const int i0 = (rb_ & 15) * 128;
    const size_t BN = (size_t)B * N;
    const size_t bN = (size_t)b * N;

    // per-row scale from pass-1 partial sums
    if (t < 128) {
        const size_t row = bN + i0 + t;
        const float l = lpart[row] + lpart[BN + row] + lpart[2*BN + row] + lpart[3*BN + row];
        const float g = gb[row];
        scl_s[t] = (1.f - g) / l;
        gvv_s[t] = g;
    }

    {
        const uint4* sq = (const uint4*)(QP + (bN + i0) * A);
        #pragma unroll
        for (int it = 0; it < 16; ++it) {
            const int idx = it * 256 + t;
            const int row = idx >> 5, c4 = idx & 31;
            const uint4 v = sq[idx];
            uint2 hh, ll;
            hh.x = (v.x & 0xffffu) | ((v.y & 0xffffu) << 16);
            hh.y = (v.z & 0xffffu) | ((v.w & 0xffffu) << 16);
            ll.x = (v.x >> 16) | (v.y & 0xffff0000u);
            ll.y = (v.z >> 16) | (v.w & 0xffff0000u);
            const int base = (row << 8) + (((c4 >> 1) << 4) ^ ((row & 7) << 4)) + (c4 & 1) * 8;
            *(uint2*)((char*)qh + base) = hh;
            *(uint2*)((char*)ql + base) = ll;
        }
    }

    for (int jt = 0; jt < 4; ++jt) {
        const int j0 = jc * 512 + jt * 128;
        __syncthreads();
        {
            const uint4* sk = (const uint4*)(KP + (bN + j0) * A);
            #pragma unroll
            for (int it = 0; it < 16; ++it) {
                const int idx = it * 256 + t;
                const int row = idx >> 5, c4 = idx & 31;
                const uint4 v = sk[idx];
                uint2 hh, ll;
                hh.x = (v.x & 0xffffu) | ((v.y & 0xffffu) << 16);
                hh.y = (v.z & 0xffffu) | ((v.w & 0xffffu) << 16);
                ll.x = (v.x >> 16) | (v.y & 0xffff0000u);
                ll.y = (v.z >> 16) | (v.w & 0xffff0000u);
                const int base = (row << 8) + (((c4 >> 1) << 4) ^ ((row & 7) << 4)) + (c4 & 1) * 8;
                *(uint2*)((char*)kh + base) = hh;
                *(uint2*)((char*)kl + base) = ll;
            }
        }
        __syncthreads();

        f32x4 acc[4][4];
        #pragma unroll
        for (int r = 0; r < 4; ++r)
            #pragma unroll
            for (int c = 0; c < 4; ++c) acc[r][c] = {0.f, 0.f, 0.f, 0.f};

        #pragma unroll
        for (int ks = 0; ks < 4; ++ks) {
            const int kb = ks * 64 + l4 * 16;
            bf16x8 ah[4], al[4], bh[4], bl[4];
            #pragma unroll
            for (int r = 0; r < 4; ++r) {
                const int row = wr * 64 + r * 16 + l15;
                const int off = (row << 8) + (kb ^ ((row & 7) << 4));
                ah[r] = *(const bf16x8*)((const char*)qh + off);
                al[r] = *(const bf16x8*)((const char*)ql + off);
            }
            #pragma unroll
            for (int c = 0; c < 4; ++c) {
                const int row = wc * 64 + c * 16 + l15;
                const int off = (row << 8) + (kb ^ ((row & 7) << 4));
                bh[c] = *(const bf16x8*)((const char*)kh + off);
                bl[c] = *(const bf16x8*)((const char*)kl + off);
            }
            #pragma unroll
            for (int r = 0; r < 4; ++r)
                #pragma unroll
                for (int c = 0; c < 4; ++c) {
                    acc[r][c] = mfma16(ah[r], bh[c], acc[r][c]);
                    acc[r][c] = mfma16(ah[r], bl[c], acc[r][c]);
                    acc[r][c] = mfma16(al[r], bh[c], acc[r][c]);
                }
        }

        #pragma unroll
        for (int r = 0; r < 4; ++r) {
            const int li = wr * 64 + r * 16 + l4 * 4;
            const int i = i0 + li;
            #pragma unroll
            for (int c = 0; c < 4; ++c) {
                const int j = j0 + wc * 64 + c * 16 + l15;
                float* dst = out + (bN + i) * N + j;
                #pragma unroll
                for (int g = 0; g < 4; ++g) {
                    const float v = (i + g == j) ? gvv_s[li + g]
                                                 : __expf(acc[r][c][g]) * scl_s[li + g];
                    dst[(size_t)g * N] = v;
                }
            }
        }
    }
}

extern "C" void kernel_launch(void* const* d_in, const int* in_sizes, int n_in,
                              void* d_out, int out_size, void* d_ws, size_t ws_size,
                              hipStream_t stream) {
    const float* x  = (const float*)d_in[0];
    const float* Wq = (const float*)d_in[1];
    const float* bq = (const float*)d_in[2];
    const float* Wk = (const float*)d_in[3];
    const float* bk = (const float*)d_in[4];
    const float* Wv = (const float*)d_in[5];
    const float* bv = (const float*)d_in[6];
    float* out = (float*)d_out;

    uint_t* QP = (uint_t*)d_ws;                          // 8 MB
    uint_t* KP = QP + (size_t)B * N * A;                 // 8 MB
    ushort_t* WqTh = (ushort_t*)(KP + (size_t)B * N * A);
    ushort_t* WqTl = WqTh + H * A;
    ushort_t* WkTh = WqTl + H * A;
    ushort_t* WkTl = WkTh + H * A;
    float* gb = (float*)(WkTl + H * A);                  // 64 KB
    float* lp = gb + (size_t)B * N;                      // 256 KB (4 partials)

    k0_conv<<<(H * A) / 256, 256, 0, stream>>>(Wq, Wk, WqTh, WqTl, WkTh, WkTl);
    k1_mfma<<<(B * N) / 64, 256, 0, stream>>>(x, WqTh, WqTl, WkTh, WkTl,
                                              bq, bk, Wv, bv, QP, KP, gb);
    k2s_mfma<<<B * (N / 128) * 4, 256, 0, stream>>>(QP, KP, lp);
    k2w_mfma<<<B * (N / 128) * 4, 256, 0, stream>>>(QP, KP, gb, lp, out);
}

// Round 8
// 126.816 us; speedup vs baseline: 1.5222x; 1.0247x over previous
//
#include <hip/hip_runtime.h>
#include <hip/hip_bf16.h>
#include <math.h>

constexpr int B = 8, N = 2048, H = 512, A = 128;

typedef __bf16 bf16x8 __attribute__((ext_vector_type(8)));
typedef float f32x4 __attribute__((ext_vector_type(4)));
typedef unsigned short ushort_t;
typedef unsigned int uint_t;

__device__ __forceinline__ f32x4 mfma16(bf16x8 a, bf16x8 b, f32x4 c) {
    return __builtin_amdgcn_mfma_f32_16x16x32_bf16(a, b, c, 0, 0, 0);
}
__device__ __forceinline__ ushort_t f2bf(float v) {
    return __builtin_bit_cast(ushort_t, __float2bfloat16(v));
}
__device__ __forceinline__ float bf2f(ushort_t u) {
    return __bfloat162float(__builtin_bit_cast(__hip_bfloat16, u));
}
// async global->LDS, 16B per lane; lds base must be wave-uniform
__device__ __forceinline__ void gload16(const void* g, void* l) {
    __builtin_amdgcn_global_load_lds(
        (__attribute__((address_space(1))) void*)(g),
        (__attribute__((address_space(3))) void*)(l), 16, 0, 0);
}

// swizzled-plane byte offset for element (row within 128-block, col in [0,128))
__device__ __forceinline__ int swz_byte(int rl, int col) {
    return (rl << 8) + ((((col >> 3) << 4) | ((col & 7) << 1)) ^ ((rl & 7) << 4));
}

// ---------------- K0: transpose + hi/lo split the weights ----------------
__global__ __launch_bounds__(256) void k0_conv(
    const float* __restrict__ Wq, const float* __restrict__ Wk,
    ushort_t* __restrict__ WqTh, ushort_t* __restrict__ WqTl,
    ushort_t* __restrict__ WkTh, ushort_t* __restrict__ WkTl)
{
    const int id = blockIdx.x * 256 + threadIdx.x;   // 65536 = 512*128
    const int k = id >> 7, n = id & 127;
    const float vq = Wq[id];
    const ushort_t qh = f2bf(vq);
    const ushort_t ql = f2bf(vq - bf2f(qh));
    WqTh[n * 512 + k] = qh; WqTl[n * 512 + k] = ql;
    const float vk = Wk[id];
    const ushort_t kh = f2bf(vk);
    const ushort_t kl = f2bf(vk - bf2f(kh));
    WkTh[n * 512 + k] = kh; WkTl[n * 512 + k] = kl;
}

// ---------------- K1: MFMA projections + gate; swizzled-plane stores ----------------
// 512 WGs x 32 rows, 4 waves: wave w -> (w<2 ? Q : K), col half (w&1). 32 KB LDS -> 2 WG/CU.
__global__ __launch_bounds__(256) void k1_mfma(
    const float* __restrict__ x,
    const ushort_t* __restrict__ WqTh, const ushort_t* __restrict__ WqTl,
    const ushort_t* __restrict__ WkTh, const ushort_t* __restrict__ WkTl,
    const float* __restrict__ bq, const float* __restrict__ bk,
    const float* __restrict__ Wv, const float* __restrict__ bv,
    ushort_t* __restrict__ QSh, ushort_t* __restrict__ QSl,
    ushort_t* __restrict__ KSh, ushort_t* __restrict__ KSl,
    float* __restrict__ gb)
{
    __shared__ ushort_t xh[32 * 256], xl[32 * 256];   // 32 KiB
    __shared__ float gred[2][32];
    const int t = threadIdx.x;
    const int lane = t & 63, w = t >> 6;
    const int l15 = lane & 15, l4 = lane >> 4;
    const int m0 = blockIdx.x * 32;

    f32x4 acc[2][4];
    #pragma unroll
    for (int r = 0; r < 2; ++r)
        #pragma unroll
        for (int c = 0; c < 4; ++c) acc[r][c] = {0.f, 0.f, 0.f, 0.f};

    const ushort_t* WTh = (w < 2) ? WqTh : WkTh;
    const ushort_t* WTl = (w < 2) ? WqTl : WkTl;
    const int colbase = (w & 1) * 64;

    for (int ck = 0; ck < 2; ++ck) {
        __syncthreads();
        // stage x[32][256] f32 -> hi/lo bf16, XOR-swizzled
        #pragma unroll
        for (int it = 0; it < 8; ++it) {
            const int idx = it * 256 + t;            // 2048 float4s
            const int row = idx >> 6, c4 = idx & 63;
            const float4 v = *(const float4*)(x + (size_t)(m0 + row) * H + ck * 256 + c4 * 4);
            const ushort_t h0 = f2bf(v.x), h1 = f2bf(v.y), h2 = f2bf(v.z), h3 = f2bf(v.w);
            const ushort_t e0 = f2bf(v.x - bf2f(h0)), e1 = f2bf(v.y - bf2f(h1));
            const ushort_t e2 = f2bf(v.z - bf2f(h2)), e3 = f2bf(v.w - bf2f(h3));
            uint2 hh, ll;
            hh.x = (uint_t)h0 | ((uint_t)h1 << 16); hh.y = (uint_t)h2 | ((uint_t)h3 << 16);
            ll.x = (uint_t)e0 | ((uint_t)e1 << 16); ll.y = (uint_t)e2 | ((uint_t)e3 << 16);
            const int base = row * 512 + ((((c4 >> 1) << 4)) ^ ((row & 7) << 4)) + (c4 & 1) * 8;
            *(uint2*)((char*)xh + base) = hh;
            *(uint2*)((char*)xl + base) = ll;
        }
        __syncthreads();

        #pragma unroll
        for (int ks = 0; ks < 8; ++ks) {
            bf16x8 ah[2], al[2], bh[4], bl[4];
            const int kb = ks * 64 + l4 * 16;
            #pragma unroll
            for (int rb = 0; rb < 2; ++rb) {
                const int row = rb * 16 + l15;
                const int off = row * 512 + (kb ^ ((row & 7) << 4));
                ah[rb] = *(const bf16x8*)((const char*)xh + off);
                al[rb] = *(const bf16x8*)((const char*)xl + off);
            }
            const int kg = ck * 256 + ks * 32 + l4 * 8;
            #pragma unroll
            for (int cb = 0; cb < 4; ++cb) {
                const size_t woff = (size_t)(colbase + cb * 16 + l15) * 512 + kg;
                bh[cb] = *(const bf16x8*)(WTh + woff);
                bl[cb] = *(const bf16x8*)(WTl + woff);
            }
            #pragma unroll
            for (int rb = 0; rb < 2; ++rb)
                #pragma unroll
                for (int cb = 0; cb < 4; ++cb) {
                    acc[rb][cb] = mfma16(ah[rb], bh[cb], acc[rb][cb]);
                    acc[rb][cb] = mfma16(ah[rb], bl[cb], acc[rb][cb]);
                    acc[rb][cb] = mfma16(al[rb], bh[cb], acc[rb][cb]);
                }
        }
    }

    const float* bias = (w < 2) ? bq : bk;
    float bb[4], wv[4];
    #pragma unroll
    for (int cb = 0; cb < 4; ++cb) {
        bb[cb] = bias[colbase + cb * 16 + l15];
        wv[cb] = Wv[colbase + cb * 16 + l15];
    }
    float p[2][4];
    #pragma unroll
    for (int rb = 0; rb < 2; ++rb)
        #pragma unroll
        for (int g = 0; g < 4; ++g) {
            float ps = 0.f;
            #pragma unroll
            for (int cb = 0; cb < 4; ++cb) {
                const float v = acc[rb][cb][g] + bb[cb];
                acc[rb][cb][g] = v;
                ps = fmaf(v, wv[cb], ps);
            }
            p[rb][g] = ps;
        }

    // stores: hi/lo planes in the exact k2-LDS image (pre-swizzled)
    ushort_t* OH = (w < 2) ? QSh : KSh;
    ushort_t* OL = (w < 2) ? QSl : KSl;
    #pragma unroll
    for (int rb = 0; rb < 2; ++rb) {
        #pragma unroll
        for (int cb = 0; cb < 4; ++cb) {
            const int col = colbase + cb * 16 + l15;
            #pragma unroll
            for (int g = 0; g < 4; ++g) {
                const int r = m0 + rb * 16 + l4 * 4 + g;
                const float v = acc[rb][cb][g];
                const ushort_t hi = f2bf(v);
                const ushort_t lo = f2bf(v - bf2f(hi));
                const size_t blkb = (size_t)(r >> 7) * 32768;   // bytes per 128-block plane
                const int byte = swz_byte(r & 127, col);
                *(ushort_t*)((char*)OH + blkb + byte) = hi;
                *(ushort_t*)((char*)OL + blkb + byte) = lo;
            }
        }
    }

    if (w < 2) {
        #pragma unroll
        for (int rb = 0; rb < 2; ++rb)
            #pragma unroll
            for (int g = 0; g < 4; ++g) {
                float v = p[rb][g];
                v += __shfl_xor(v, 1); v += __shfl_xor(v, 2);
                v += __shfl_xor(v, 4); v += __shfl_xor(v, 8);
                if (l15 == 0) gred[w][rb * 16 + l4 * 4 + g] = v;
            }
    }
    __syncthreads();
    if (t < 32) {
        const float z = gred[0][t] + gred[1][t] + bv[0];
        gb[m0 + t] = 1.f / (1.f + __expf(-z));
    }
}

// ---------------- K2s: pass 1 — scores -> exp -> partial row sums ----------------
// grid 512: b = bid&7 (XCD-pinned), jc = (bid>>3)>>4, i-block = (bid>>3)&15.
__global__ __launch_bounds__(256) void k2s_mfma(
    const ushort_t* __restrict__ QSh, const ushort_t* __restrict__ QSl,
    const ushort_t* __restrict__ KSh, const ushort_t* __restrict__ KSl,
    float* __restrict__ lpart)
{
    __shared__ ushort_t qh[128*128], ql[128*128], kh[128*128], kl[128*128]; // 128 KiB
    const int t = threadIdx.x;
    const int lane = t & 63, wid = t >> 6;
    const int wr = wid >> 1, wc = wid & 1;
    const int l15 = lane & 15, l4 = lane >> 4;

    const int b    = blockIdx.x & 7;
    const int rest = blockIdx.x >> 3;
    const int jc   = rest >> 4;
    const int i0   = (rest & 15) << 7;

    // stage Q tile once: direct global->LDS (planes already in LDS image)
    {
        const int qblk = (b << 4) + (i0 >> 7);
        const char* sh = (const char*)(QSh + (size_t)qblk * 16384);
        const char* sl = (const char*)(QSl + (size_t)qblk * 16384);
        const int base = wid * 8192;
        #pragma unroll
        for (int it = 0; it < 8; ++it) {
            const int o = base + it * 1024;
            gload16(sh + o + lane * 16, (char*)qh + o);
            gload16(sl + o + lane * 16, (char*)ql + o);
        }
    }

    float lsum[16];
    #pragma unroll
    for (int u = 0; u < 16; ++u) lsum[u] = 0.f;

    for (int jt = 0; jt < 4; ++jt) {
        const int j0 = jc * 512 + jt * 128;
        __syncthreads();                       // prev readers done (drains Q at jt=0)
        {
            const int kblk = (b << 4) + (jc << 2) + jt;
            const char* sh = (const char*)(KSh + (size_t)kblk * 16384);
            const char* sl = (const char*)(KSl + (size_t)kblk * 16384);
            const int base = wid * 8192;
            #pragma unroll
            for (int it = 0; it < 8; ++it) {
                const int o = base + it * 1024;
                gload16(sh + o + lane * 16, (char*)kh + o);
                gload16(sl + o + lane * 16, (char*)kl + o);
            }
        }
        __syncthreads();                       // waits vmcnt(0): tiles resident

        f32x4 acc[4][4];
        #pragma unroll
        for (int r = 0; r < 4; ++r)
            #pragma unroll
            for (int c = 0; c < 4; ++c) acc[r][c] = {0.f, 0.f, 0.f, 0.f};

        #pragma unroll
        for (int ks = 0; ks < 4; ++ks) {
            const int kb = ks * 64 + l4 * 16;
            bf16x8 ah[4], al[4], bh[4], bl[4];
            #pragma unroll
            for (int r = 0; r < 4; ++r) {
                const int row = wr * 64 + r * 16 + l15;
                const int off = (row << 8) + (kb ^ ((row & 7) << 4));
                ah[r] = *(const bf16x8*)((const char*)qh + off);
                al[r] = *(const bf16x8*)((const char*)ql + off);
            }
            #pragma unroll
            for (int c = 0; c < 4; ++c) {
                const int row = wc * 64 + c * 16 + l15;
                const int off = (row << 8) + (kb ^ ((row & 7) << 4));
                bh[c] = *(const bf16x8*)((const char*)kh + off);
                bl[c] = *(const bf16x8*)((const char*)kl + off);
            }
            #pragma unroll
            for (int r = 0; r < 4; ++r)
                #pragma unroll
                for (int c = 0; c < 4; ++c) {
                    acc[r][c] = mfma16(ah[r], bh[c], acc[r][c]);
                    acc[r][c] = mfma16(ah[r], bl[c], acc[r][c]);
                    acc[r][c] = mfma16(al[r], bh[c], acc[r][c]);
                }
        }

        #pragma unroll
        for (int r = 0; r < 4; ++r) {
            const int i = i0 + wr * 64 + r * 16 + l4 * 4;
            #pragma unroll
            for (int c = 0; c < 4; ++c) {
                const int j = j0 + wc * 64 + c * 16 + l15;
                #pragma unroll
                for (int g = 0; g < 4; ++g) {
                    const float e = (i + g == j) ? 0.f : __expf(acc[r][c][g]);
                    lsum[r * 4 + g] += e;
                }
            }
        }
    }

    __syncthreads();
    float* lred = (float*)kh;
    #pragma unroll
    for (int r = 0; r < 4; ++r)
        #pragma unroll
        for (int g = 0; g < 4; ++g) {
            float v = lsum[r * 4 + g];
            v += __shfl_xor(v, 1); v += __shfl_xor(v, 2);
            v += __shfl_xor(v, 4); v += __shfl_xor(v, 8);
            if (l15 == 0) lred[wc * 128 + wr * 64 + r * 16 + l4 * 4 + g] = v;
        }
    __syncthreads();
    if (t < 128)
        lpart[(size_t)jc * (B * N) + (size_t)b * N + i0 + t] = lred[t] + lred[128 + t];
}

// ---------------- K2w: pass 2 — recompute scores -> normalize -> f32 out ----------------
__global__ __launch_bounds__(256) void k2w_mfma(
    const ushort_t* __restrict__ QSh, const ushort_t* __restrict__ QSl,
    const ushort_t* __restrict__ KSh, const ushort_t* __restrict__ KSl,
    const float* __restrict__ gb, const float* __restrict__ lpart,
    float* __restrict__ out)
{
    __shared__ ushort_t qh[128*128], ql[128*128], kh[128*128], kl[128*128]; // 128 KiB
    __shared__ float scl_s[128], gvv_s[128];
    const int t = threadIdx.x;
    const int lane = t & 63, wid = t >> 6;
    const int wr = wid >> 1, wc = wid & 1;
    const int l15 = lane & 15, l4 = lane >> 4;

    const int b    = blockIdx.x & 7;
    const int rest = blockIdx.x >> 3;
    const int jc   = rest >> 4;
    const int i0   = (rest & 15) << 7;
    const size_t BN = (size_t)B * N;
    const size_t bN = (size_t)b * N;

    if (t < 128) {
        const size_t row = bN + i0 + t;
        const float l = lpart[row] + lpart[BN + row] + lpart[2*BN + row] + lpart[3*BN + row];
        const float g = gb[row];
        scl_s[t] = (1.f - g) / l;
        gvv_s[t] = g;
    }

    {
        const int qblk = (b << 4) + (i0 >> 7);
        const char* sh = (const char*)(QSh + (size_t)qblk * 16384);
        const char* sl = (const char*)(QSl + (size_t)qblk * 16384);
        const int base = wid * 8192;
        #pragma unroll
        for (int it = 0; it < 8; ++it) {
            const int o = base + it * 1024;
            gload16(sh + o + lane * 16, (char*)qh + o);
            gload16(sl + o + lane * 16, (char*)ql + o);
        }
    }

    for (int jt = 0; jt < 4; ++jt) {
        const int j0 = jc * 512 + jt * 128;
        __syncthreads();
        {
            const int kblk = (b << 4) + (jc << 2) + jt;
            const char* sh = (const char*)(KSh + (size_t)kblk * 16384);
            const char* sl = (const char*)(KSl + (size_t)kblk * 16384);
            const int base = wid * 8192;
            #pragma unroll
            for (int it = 0; it < 8; ++it) {
                const int o = base + it * 1024;
                gload16(sh + o + lane * 16, (char*)kh + o);
                gload16(sl + o + lane * 16, (char*)kl + o);
            }
        }
        __syncthreads();

        f32x4 acc[4][4];
        #pragma unroll
        for (int r = 0; r < 4; ++r)
            #pragma unroll
            for (int c = 0; c < 4; ++c) acc[r][c] = {0.f, 0.f, 0.f, 0.f};

        #pragma unroll
        for (int ks = 0; ks < 4; ++ks) {
            const int kb = ks * 64 + l4 * 16;
            bf16x8 ah[4], al[4], bh[4], bl[4];
            #pragma unroll
            for (int r = 0; r < 4; ++r) {
                const int row = wr * 64 + r * 16 + l15;
                const int off = (row << 8) + (kb ^ ((row & 7) << 4));
                ah[r] = *(const bf16x8*)((const char*)qh + off);
                al[r] = *(const bf16x8*)((const char*)ql + off);
            }
            #pragma unroll
            for (int c = 0; c < 4; ++c) {
                const int row = wc * 64 + c * 16 + l15;
                const int off = (row << 8) + (kb ^ ((row & 7) << 4));
                bh[c] = *(const bf16x8*)((const char*)kh + off);
                bl[c] = *(const bf16x8*)((const char*)kl + off);
            }
            #pragma unroll
            for (int r = 0; r < 4; ++r)
                #pragma unroll
                for (int c = 0; c < 4; ++c) {
                    acc[r][c] = mfma16(ah[r], bh[c], acc[r][c]);
                    acc[r][c] = mfma16(ah[r], bl[c], acc[r][c]);
                    acc[r][c] = mfma16(al[r], bh[c], acc[r][c]);
                }
        }

        #pragma unroll
        for (int r = 0; r < 4; ++r) {
            const int li = wr * 64 + r * 16 + l4 * 4;
            const int i = i0 + li;
            #pragma unroll
            for (int c = 0; c < 4; ++c) {
                const int j = j0 + wc * 64 + c * 16 + l15;
                float* dst = out + (bN + i) * N + j;
                #pragma unroll
                for (int g = 0; g < 4; ++g) {
                    const float v = (i + g == j) ? gvv_s[li + g]
                                                 : __expf(acc[r][c][g]) * scl_s[li + g];
                    dst[(size_t)g * N] = v;
                }
            }
        }
    }
}

extern "C" void kernel_launch(void* const* d_in, const int* in_sizes, int n_in,
                              void* d_out, int out_size, void* d_ws, size_t ws_size,
                              hipStream_t stream) {
    const float* x  = (const float*)d_in[0];
    const float* Wq = (const float*)d_in[1];
    const float* bq = (const float*)d_in[2];
    const float* Wk = (const float*)d_in[3];
    const float* bk = (const float*)d_in[4];
    const float* Wv = (const float*)d_in[5];
    const float* bv = (const float*)d_in[6];
    float* out = (float*)d_out;

    const size_t PL = (size_t)B * N * A;                 // 2M elems / plane (4 MB)
    ushort_t* QSh = (ushort_t*)d_ws;
    ushort_t* QSl = QSh + PL;
    ushort_t* KSh = QSl + PL;
    ushort_t* KSl = KSh + PL;
    ushort_t* WqTh = KSl + PL;
    ushort_t* WqTl = WqTh + H * A;
    ushort_t* WkTh = WqTl + H * A;
    ushort_t* WkTl = WkTh + H * A;
    float* gb = (float*)(WkTl + H * A);                  // 64 KB
    float* lp = gb + (size_t)B * N;                      // 256 KB (4 partials)

    k0_conv<<<(H * A) / 256, 256, 0, stream>>>(Wq, Wk, WqTh, WqTl, WkTh, WkTl);
    k1_mfma<<<(B * N) / 32, 256, 0, stream>>>(x, WqTh, WqTl, WkTh, WkTl,
                                              bq, bk, Wv, bv, QSh, QSl, KSh, KSl, gb);
    k2s_mfma<<<512, 256, 0, stream>>>(QSh, QSl, KSh, KSl, lp);
    k2w_mfma<<<512, 256, 0, stream>>>(QSh, QSl, KSh, KSl, gb, lp, out);
}

// Round 9
// 95.210 us; speedup vs baseline: 2.0275x; 1.3320x over previous
//
#include <hip/hip_runtime.h>
#include <hip/hip_bf16.h>
#include <math.h>

constexpr int B = 8, N = 2048, H = 512, A = 128;

typedef _Float16 f16x8 __attribute__((ext_vector_type(8)));
typedef float f32x4 __attribute__((ext_vector_type(4)));
typedef unsigned short ushort_t;
typedef unsigned int uint_t;

__device__ __forceinline__ f32x4 mfma16h(f16x8 a, f16x8 b, f32x4 c) {
    return __builtin_amdgcn_mfma_f32_16x16x32_f16(a, b, c, 0, 0, 0);
}
__device__ __forceinline__ ushort_t f2h(float v) {
    return __builtin_bit_cast(ushort_t, (_Float16)v);
}
__device__ __forceinline__ float h2f(ushort_t u) {
    return (float)__builtin_bit_cast(_Float16, u);
}
// async global->LDS, 16B per lane; lds base must be wave-uniform
__device__ __forceinline__ void gload16(const void* g, void* l) {
    __builtin_amdgcn_global_load_lds(
        (__attribute__((address_space(1))) void*)(g),
        (__attribute__((address_space(3))) void*)(l), 16, 0, 0);
}
// swizzled-plane byte offset for element (row within 128-block, col in [0,128))
__device__ __forceinline__ int swz_byte(int rl, int col) {
    return (rl << 8) + ((((col >> 3) << 4) | ((col & 7) << 1)) ^ ((rl & 7) << 4));
}

// ---------------- K0: transpose weights to fp16 ----------------
__global__ __launch_bounds__(256) void k0_conv(
    const float* __restrict__ Wq, const float* __restrict__ Wk,
    ushort_t* __restrict__ WqT, ushort_t* __restrict__ WkT)
{
    const int id = blockIdx.x * 256 + threadIdx.x;   // 65536 = 512*128
    const int k = id >> 7, n = id & 127;
    WqT[n * 512 + k] = f2h(Wq[id]);
    WkT[n * 512 + k] = f2h(Wk[id]);
}

// ---------------- K1: MFMA projections + gate; swizzled fp16-plane stores ----------------
// 512 WGs x 32 rows, 4 waves: wave w -> (w<2 ? Q : K), col half (w&1).
__global__ __launch_bounds__(256) void k1_mfma(
    const float* __restrict__ x,
    const ushort_t* __restrict__ WqT, const ushort_t* __restrict__ WkT,
    const float* __restrict__ bq, const float* __restrict__ bk,
    const float* __restrict__ Wv, const float* __restrict__ bv,
    ushort_t* __restrict__ QSh, ushort_t* __restrict__ QSl,
    ushort_t* __restrict__ KSh, float* __restrict__ gb)
{
    __shared__ ushort_t xh[32 * 256], xl[32 * 256];   // 32 KiB
    __shared__ float gred[2][32];
    const int t = threadIdx.x;
    const int lane = t & 63, w = t >> 6;
    const int l15 = lane & 15, l4 = lane >> 4;
    const int m0 = blockIdx.x * 32;

    f32x4 acc[2][4];
    #pragma unroll
    for (int r = 0; r < 2; ++r)
        #pragma unroll
        for (int c = 0; c < 4; ++c) acc[r][c] = {0.f, 0.f, 0.f, 0.f};

    const ushort_t* WT = (w < 2) ? WqT : WkT;
    const int colbase = (w & 1) * 64;

    for (int ck = 0; ck < 2; ++ck) {
        __syncthreads();
        // stage x[32][256] f32 -> hi/lo fp16, XOR-swizzled
        #pragma unroll
        for (int it = 0; it < 8; ++it) {
            const int idx = it * 256 + t;            // 2048 float4s
            const int row = idx >> 6, c4 = idx & 63;
            const float4 v = *(const float4*)(x + (size_t)(m0 + row) * H + ck * 256 + c4 * 4);
            const ushort_t h0 = f2h(v.x), h1 = f2h(v.y), h2 = f2h(v.z), h3 = f2h(v.w);
            const ushort_t e0 = f2h(v.x - h2f(h0)), e1 = f2h(v.y - h2f(h1));
            const ushort_t e2 = f2h(v.z - h2f(h2)), e3 = f2h(v.w - h2f(h3));
            uint2 hh, ll;
            hh.x = (uint_t)h0 | ((uint_t)h1 << 16); hh.y = (uint_t)h2 | ((uint_t)h3 << 16);
            ll.x = (uint_t)e0 | ((uint_t)e1 << 16); ll.y = (uint_t)e2 | ((uint_t)e3 << 16);
            const int base = row * 512 + ((((c4 >> 1) << 4)) ^ ((row & 7) << 4)) + (c4 & 1) * 8;
            *(uint2*)((char*)xh + base) = hh;
            *(uint2*)((char*)xl + base) = ll;
        }
        __syncthreads();

        #pragma unroll
        for (int ks = 0; ks < 8; ++ks) {
            f16x8 ah[2], al[2], bh[4];
            const int kb = ks * 64 + l4 * 16;
            #pragma unroll
            for (int rb = 0; rb < 2; ++rb) {
                const int row = rb * 16 + l15;
                const int off = row * 512 + (kb ^ ((row & 7) << 4));
                ah[rb] = *(const f16x8*)((const char*)xh + off);
                al[rb] = *(const f16x8*)((const char*)xl + off);
            }
            const int kg = ck * 256 + ks * 32 + l4 * 8;
            #pragma unroll
            for (int cb = 0; cb < 4; ++cb)
                bh[cb] = *(const f16x8*)(WT + (size_t)(colbase + cb * 16 + l15) * 512 + kg);
            #pragma unroll
            for (int rb = 0; rb < 2; ++rb)
                #pragma unroll
                for (int cb = 0; cb < 4; ++cb) {
                    acc[rb][cb] = mfma16h(ah[rb], bh[cb], acc[rb][cb]);
                    acc[rb][cb] = mfma16h(al[rb], bh[cb], acc[rb][cb]);
                }
        }
    }

    const float* bias = (w < 2) ? bq : bk;
    float bb[4], wv[4];
    #pragma unroll
    for (int cb = 0; cb < 4; ++cb) {
        bb[cb] = bias[colbase + cb * 16 + l15];
        wv[cb] = Wv[colbase + cb * 16 + l15];
    }
    float p[2][4];
    #pragma unroll
    for (int rb = 0; rb < 2; ++rb)
        #pragma unroll
        for (int g = 0; g < 4; ++g) {
            float ps = 0.f;
            #pragma unroll
            for (int cb = 0; cb < 4; ++cb) {
                const float v = acc[rb][cb][g] + bb[cb];
                acc[rb][cb][g] = v;
                ps = fmaf(v, wv[cb], ps);
            }
            p[rb][g] = ps;
        }

    // stores into the k2 LDS image (pre-swizzled fp16 planes)
    #pragma unroll
    for (int rb = 0; rb < 2; ++rb) {
        #pragma unroll
        for (int cb = 0; cb < 4; ++cb) {
            const int col = colbase + cb * 16 + l15;
            #pragma unroll
            for (int g = 0; g < 4; ++g) {
                const int r = m0 + rb * 16 + l4 * 4 + g;
                const float v = acc[rb][cb][g];
                const size_t blkb = (size_t)(r >> 7) * 32768;
                const int byte = swz_byte(r & 127, col);
                if (w < 2) {
                    const ushort_t hi = f2h(v);
                    *(ushort_t*)((char*)QSh + blkb + byte) = hi;
                    *(ushort_t*)((char*)QSl + blkb + byte) = f2h(v - h2f(hi));
                } else {
                    *(ushort_t*)((char*)KSh + blkb + byte) = f2h(v);
                }
            }
        }
    }

    if (w < 2) {
        #pragma unroll
        for (int rb = 0; rb < 2; ++rb)
            #pragma unroll
            for (int g = 0; g < 4; ++g) {
                float v = p[rb][g];
                v += __shfl_xor(v, 1); v += __shfl_xor(v, 2);
                v += __shfl_xor(v, 4); v += __shfl_xor(v, 8);
                if (l15 == 0) gred[w][rb * 16 + l4 * 4 + g] = v;
            }
    }
    __syncthreads();
    if (t < 32) {
        const float z = gred[0][t] + gred[1][t] + bv[0];
        gb[m0 + t] = 1.f / (1.f + __expf(-z));
    }
}

// ---------------- K2s: pass 1 — scores -> exp -> partial row sums ----------------
// Swapped operands: A=K (j rows), B=Q (i rows). acc lane: i=l15, j=l4*4+g.
__global__ __launch_bounds__(256) void k2s_mfma(
    const ushort_t* __restrict__ QSh, const ushort_t* __restrict__ QSl,
    const ushort_t* __restrict__ KSh, float* __restrict__ lpart)
{
    __shared__ ushort_t qh[16384], ql[16384], kh[2][16384];   // 128 KiB
    const int t = threadIdx.x;
    const int lane = t & 63, wid = t >> 6;
    const int wr = wid >> 1, wc = wid & 1;     // wr: j-half, wc: i-half
    const int l15 = lane & 15, l4 = lane >> 4;

    const int b    = blockIdx.x & 7;
    const int rest = blockIdx.x >> 3;
    const int jc   = rest >> 4;
    const int i0   = (rest & 15) << 7;

    // prologue: stage Q (2 planes) + K tile 0
    {
        const int qblk = (b << 4) + (i0 >> 7);
        const char* sh = (const char*)(QSh + (size_t)qblk * 16384);
        const char* sl = (const char*)(QSl + (size_t)qblk * 16384);
        const int kblk = (b << 4) + (jc << 2);
        const char* sk = (const char*)(KSh + (size_t)kblk * 16384);
        const int base = wid * 8192;
        #pragma unroll
        for (int it = 0; it < 8; ++it) {
            const int o = base + it * 1024;
            gload16(sh + o + lane * 16, (char*)qh + o);
            gload16(sl + o + lane * 16, (char*)ql + o);
            gload16(sk + o + lane * 16, (char*)kh[0] + o);
        }
    }
    __syncthreads();

    float lsum[4] = {0.f, 0.f, 0.f, 0.f};     // per c (i-frag)

    for (int jt = 0; jt < 4; ++jt) {
        if (jt < 3) {   // prefetch next K tile into the other buffer
            const int kblk = (b << 4) + (jc << 2) + jt + 1;
            const char* sk = (const char*)(KSh + (size_t)kblk * 16384);
            const int base = wid * 8192;
            #pragma unroll
            for (int it = 0; it < 8; ++it) {
                const int o = base + it * 1024;
                gload16(sk + o + lane * 16, (char*)kh[(jt + 1) & 1] + o);
            }
        }
        const char* kcur = (const char*)kh[jt & 1];
        const int j0 = jc * 512 + jt * 128;

        f32x4 acc[4][4];
        #pragma unroll
        for (int r = 0; r < 4; ++r)
            #pragma unroll
            for (int c = 0; c < 4; ++c) acc[r][c] = {0.f, 0.f, 0.f, 0.f};

        #pragma unroll
        for (int ks = 0; ks < 4; ++ks) {
            const int kb = ks * 64 + l4 * 16;
            f16x8 ak[4], bqh[4], bql[4];
            #pragma unroll
            for (int r = 0; r < 4; ++r) {
                const int row = wr * 64 + r * 16 + l15;
                ak[r] = *(const f16x8*)(kcur + (row << 8) + (kb ^ ((row & 7) << 4)));
            }
            #pragma unroll
            for (int c = 0; c < 4; ++c) {
                const int row = wc * 64 + c * 16 + l15;
                const int off = (row << 8) + (kb ^ ((row & 7) << 4));
                bqh[c] = *(const f16x8*)((const char*)qh + off);
                bql[c] = *(const f16x8*)((const char*)ql + off);
            }
            #pragma unroll
            for (int r = 0; r < 4; ++r)
                #pragma unroll
                for (int c = 0; c < 4; ++c) {
                    acc[r][c] = mfma16h(ak[r], bqh[c], acc[r][c]);
                    acc[r][c] = mfma16h(ak[r], bql[c], acc[r][c]);
                }
        }

        #pragma unroll
        for (int r = 0; r < 4; ++r) {
            const int jb = j0 + wr * 64 + r * 16 + l4 * 4;
            #pragma unroll
            for (int c = 0; c < 4; ++c) {
                const int i = i0 + wc * 64 + c * 16 + l15;
                #pragma unroll
                for (int g = 0; g < 4; ++g) {
                    const float e = (jb + g == i) ? 0.f : __expf(acc[r][c][g]);
                    lsum[c] += e;
                }
            }
        }
        __syncthreads();
    }

    // reduce: lanes same l15 across l4 groups, then across wr waves via LDS
    float* lred = (float*)kh;    // safe: all compute done (loop-end barrier)
    #pragma unroll
    for (int c = 0; c < 4; ++c) {
        float v = lsum[c];
        v += __shfl_xor(v, 16); v += __shfl_xor(v, 32);
        if (lane < 16) lred[wid * 64 + c * 16 + l15] = v;
    }
    __syncthreads();
    if (t < 128) {
        const int wcb = t >> 6, cl = t & 63;
        const float l = lred[wcb * 64 + cl] + lred[(2 + wcb) * 64 + cl];
        lpart[(size_t)jc * (B * N) + (size_t)b * N + i0 + t] = l;
    }
}

// ---------------- K2w: pass 2 — recompute -> normalize -> coalesced f32 out ----------------
__global__ __launch_bounds__(256) void k2w_mfma(
    const ushort_t* __restrict__ QSh, const ushort_t* __restrict__ QSl,
    const ushort_t* __restrict__ KSh,
    const float* __restrict__ gb, const float* __restrict__ lpart,
    float* __restrict__ out)
{
    __shared__ ushort_t qh[16384], ql[16384], kh[2][16384];   // 128 KiB
    __shared__ float scl_s[128], gvv_s[128];
    const int t = threadIdx.x;
    const int lane = t & 63, wid = t >> 6;
    const int wr = wid >> 1, wc = wid & 1;
    const int l15 = lane & 15, l4 = lane >> 4;

    const int b    = blockIdx.x & 7;
    const int rest = blockIdx.x >> 3;
    const int jc   = rest >> 4;
    const int i0   = (rest & 15) << 7;
    const size_t BN = (size_t)B * N;
    const size_t bN = (size_t)b * N;

    if (t < 128) {
        const size_t row = bN + i0 + t;
        const float l = lpart[row] + lpart[BN + row] + lpart[2*BN + row] + lpart[3*BN + row];
        const float g = gb[row];
        scl_s[t] = (1.f - g) / l;
        gvv_s[t] = g;
    }

    {
        const int qblk = (b << 4) + (i0 >> 7);
        const char* sh = (const char*)(QSh + (size_t)qblk * 16384);
        const char* sl = (const char*)(QSl + (size_t)qblk * 16384);
        const int kblk = (b << 4) + (jc << 2);
        const char* sk = (const char*)(KSh + (size_t)kblk * 16384);
        const int base = wid * 8192;
        #pragma unroll
        for (int it = 0; it < 8; ++it) {
            const int o = base + it * 1024;
            gload16(sh + o + lane * 16, (char*)qh + o);
            gload16(sl + o + lane * 16, (char*)ql + o);
            gload16(sk + o + lane * 16, (char*)kh[0] + o);
        }
    }
    __syncthreads();

    for (int jt = 0; jt < 4; ++jt) {
        if (jt < 3) {
            const int kblk = (b << 4) + (jc << 2) + jt + 1;
            const char* sk = (const char*)(KSh + (size_t)kblk * 16384);
            const int base = wid * 8192;
            #pragma unroll
            for (int it = 0; it < 8; ++it) {
                const int o = base + it * 1024;
                gload16(sk + o + lane * 16, (char*)kh[(jt + 1) & 1] + o);
            }
        }
        const char* kcur = (const char*)kh[jt & 1];
        const int j0 = jc * 512 + jt * 128;

        f32x4 acc[4][4];
        #pragma unroll
        for (int r = 0; r < 4; ++r)
            #pragma unroll
            for (int c = 0; c < 4; ++c) acc[r][c] = {0.f, 0.f, 0.f, 0.f};

        #pragma unroll
        for (int ks = 0; ks < 4; ++ks) {
            const int kb = ks * 64 + l4 * 16;
            f16x8 ak[4], bqh[4], bql[4];
            #pragma unroll
            for (int r = 0; r < 4; ++r) {
                const int row = wr * 64 + r * 16 + l15;
                ak[r] = *(const f16x8*)(kcur + (row << 8) + (kb ^ ((row & 7) << 4)));
            }
            #pragma unroll
            for (int c = 0; c < 4; ++c) {
                const int row = wc * 64 + c * 16 + l15;
                const int off = (row << 8) + (kb ^ ((row & 7) << 4));
                bqh[c] = *(const f16x8*)((const char*)qh + off);
                bql[c] = *(const f16x8*)((const char*)ql + off);
            }
            #pragma unroll
            for (int r = 0; r < 4; ++r)
                #pragma unroll
                for (int c = 0; c < 4; ++c) {
                    acc[r][c] = mfma16h(ak[r], bqh[c], acc[r][c]);
                    acc[r][c] = mfma16h(ak[r], bql[c], acc[r][c]);
                }
        }

        // epilogue: lane holds row i = i0+wc*64+c*16+l15, cols jb..jb+3 -> float4
        #pragma unroll
        for (int r = 0; r < 4; ++r) {
            const int jb = j0 + wr * 64 + r * 16 + l4 * 4;
            #pragma unroll
            for (int c = 0; c < 4; ++c) {
                const int li = wc * 64 + c * 16 + l15;
                const int i = i0 + li;
                const float sc = scl_s[li], gv = gvv_s[li];
                float4 o;
                o.x = (jb + 0 == i) ? gv : __expf(acc[r][c][0]) * sc;
                o.y = (jb + 1 == i) ? gv : __expf(acc[r][c][1]) * sc;
                o.z = (jb + 2 == i) ? gv : __expf(acc[r][c][2]) * sc;
                o.w = (jb + 3 == i) ? gv : __expf(acc[r][c][3]) * sc;
                *(float4*)(out + (bN + i) * N + jb) = o;
            }
        }
        __syncthreads();
    }
}

extern "C" void kernel_launch(void* const* d_in, const int* in_sizes, int n_in,
                              void* d_out, int out_size, void* d_ws, size_t ws_size,
                              hipStream_t stream) {
    const float* x  = (const float*)d_in[0];
    const float* Wq = (const float*)d_in[1];
    const float* bq = (const float*)d_in[2];
    const float* Wk = (const float*)d_in[3];
    const float* bk = (const float*)d_in[4];
    const float* Wv = (const float*)d_in[5];
    const float* bv = (const float*)d_in[6];
    float* out = (float*)d_out;

    const size_t PL = (size_t)B * N * A;                 // elems / plane (4 MB)
    ushort_t* QSh = (ushort_t*)d_ws;
    ushort_t* QSl = QSh + PL;
    ushort_t* KSh = QSl + PL;
    ushort_t* WqT = KSh + PL;
    ushort_t* WkT = WqT + H * A;
    float* gb = (float*)(WkT + H * A);                   // 64 KB
    float* lp = gb + (size_t)B * N;                      // 256 KB (4 partials)

    k0_conv<<<(H * A) / 256, 256, 0, stream>>>(Wq, Wk, WqT, WkT);
    k1_mfma<<<(B * N) / 32, 256, 0, stream>>>(x, WqT, WkT, bq, bk, Wv, bv,
                                              QSh, QSl, KSh, gb);
    k2s_mfma<<<512, 256, 0, stream>>>(QSh, QSl, KSh, lp);
    k2w_mfma<<<512, 256, 0, stream>>>(QSh, QSl, KSh, gb, lp, out);
}